// Round 1
// baseline (220.420 us; speedup 1.0000x reference)
//
#include <hip/hip_runtime.h>
#include <hip/hip_bf16.h>
#include <stdint.h>

typedef __attribute__((ext_vector_type(8))) short short8;
typedef __attribute__((ext_vector_type(4))) float f32x4;
typedef unsigned short u16;
typedef unsigned int u32;

static constexpr int S = 2048;
static constexpr int H = 16;
static constexpr int HD = 64;

__device__ __forceinline__ u16 f2bf(float f){
  union { float f; u32 u; } x; x.f = f;
  u32 r = x.u + 0x7fffu + ((x.u >> 16) & 1u);
  return (u16)(r >> 16);
}

__global__ __launch_bounds__(256) void cast_f32_bf16(const float* __restrict__ src,
                                                     u16* __restrict__ dst, int n){
  int i = (blockIdx.x * 256 + threadIdx.x) * 4;
  if (i >= n) return;
  float4 v = *(const float4*)(src + i);
  ushort4 o;
  o.x = f2bf(v.x); o.y = f2bf(v.y); o.z = f2bf(v.z); o.w = f2bf(v.w);
  *(ushort4*)(dst + i) = o;
}

__device__ __forceinline__ void gload_lds16(const void* g, void* lds_uniform){
  __builtin_amdgcn_global_load_lds(
      (const __attribute__((address_space(1))) u32*)g,
      (__attribute__((address_space(3))) u32*)lds_uniform,
      16, 0, 0);
}

// C = A * W^T + bias.  A: [M x 1024] bf16 row-major. W: [1024 x 1024] bf16 (out,in).
// EPI==0: write bf16 permuted [B,H,S,HD] (QKV). EPI==1: write fp32 [M,1024].
template<int EPI>
__global__ __launch_bounds__(256) void gemm_bt(const u16* __restrict__ A,
                                               const u16* __restrict__ Wall,
                                               const float* __restrict__ b0p,
                                               const float* __restrict__ b1p,
                                               const float* __restrict__ b2p,
                                               u16* __restrict__ obf,
                                               float* __restrict__ ofp){
  __shared__ __align__(16) u16 As[128*32];
  __shared__ __align__(16) u16 Bs[128*32];

  const int tid  = threadIdx.x;
  const int lane = tid & 63;
  const int wid  = tid >> 6;
  const int wm = wid >> 1, wn = wid & 1;
  const int l4 = lane >> 4, l15 = lane & 15;
  const int m0 = blockIdx.y * 128;
  const int n0 = blockIdx.x * 128;
  const int z  = blockIdx.z;

  const u16* Bw = Wall + (size_t)z * (1024*1024);
  const float* bias = (z == 0) ? b0p : ((z == 1) ? b1p : b2p);

  f32x4 acc[4][4];
  #pragma unroll
  for (int m=0;m<4;m++)
    #pragma unroll
    for (int n=0;n<4;n++) acc[m][n] = (f32x4){0.f,0.f,0.f,0.f};

  const char* Ab = (const char*)A  + (size_t)m0 * 2048;   // row stride = 1024*2B
  const char* Bb = (const char*)Bw + (size_t)n0 * 2048;
  char* AsB = (char*)As;
  char* BsB = (char*)Bs;

  int ldsu[2], row_[2], col_[2];
  #pragma unroll
  for (int p=0;p<2;p++){
    ldsu[p] = wid*1024 + p*4096;          // wave-uniform LDS byte base
    int b = ldsu[p] + lane*16;            // this lane's 16B chunk
    row_[p] = b >> 6;                     // tile row (64B per row: 32 bf16)
    col_[p] = b & 63;                     // byte within row
  }

  for (int kt = 0; kt < 32; ++kt){
    const int kb = kt * 64;               // K byte offset
    #pragma unroll
    for (int p=0;p<2;p++){
      gload_lds16(Ab + (size_t)row_[p]*2048 + kb + col_[p], AsB + ldsu[p]);
      gload_lds16(Bb + (size_t)row_[p]*2048 + kb + col_[p], BsB + ldsu[p]);
    }
    __syncthreads();

    short8 af[4], bfr[4];
    const int kcol = 8 * l4;
    #pragma unroll
    for (int m=0;m<4;m++)
      af[m] = *(const short8*)&As[(wm*64 + m*16 + l15)*32 + kcol];
    #pragma unroll
    for (int n=0;n<4;n++)
      bfr[n] = *(const short8*)&Bs[(wn*64 + n*16 + l15)*32 + kcol];

    #pragma unroll
    for (int m=0;m<4;m++)
      #pragma unroll
      for (int n=0;n<4;n++)
        acc[m][n] = __builtin_amdgcn_mfma_f32_16x16x32_bf16(af[m], bfr[n], acc[m][n], 0,0,0);

    __syncthreads();
  }

  #pragma unroll
  for (int m=0;m<4;m++){
    const int rgb = m0 + wm*64 + m*16 + 4*l4;
    #pragma unroll
    for (int n=0;n<4;n++){
      const int cg = n0 + wn*64 + n*16 + l15;
      const float bb = bias[cg];
      #pragma unroll
      for (int r=0;r<4;r++){
        const int rg = rgb + r;
        const float v = acc[m][n][r] + bb;
        if (EPI == 0){
          const int bi = rg >> 11, si = rg & 2047;
          const int hi = cg >> 6,  hd = cg & 63;
          u16* outz = obf + (size_t)z * 4194304u;
          outz[(((size_t)(bi*16 + hi))*2048 + si)*64 + hd] = f2bf(v);
        } else {
          ofp[(size_t)rg*1024 + cg] = v;
        }
      }
    }
  }
}

// Flash attention. Q,K,V: bf16 [B,H,S,HD]. Out: bf16 [B,S,H,HD].
// grid = (S/64, B*H), 256 threads (4 waves x 16 q-rows).
__global__ __launch_bounds__(256) void attn_fwd(const u16* __restrict__ Qg,
                                                const u16* __restrict__ Kg,
                                                const u16* __restrict__ Vg,
                                                u16* __restrict__ Og){
  __shared__ __align__(16) u16 Ks[64*64];      // XOR-swizzled rows
  __shared__ __align__(16) u16 Vs[64*64];      // linear
  __shared__ __align__(16) u16 Ps[4*16*64];    // per-wave P, swizzled

  const int tid  = threadIdx.x;
  const int lane = tid & 63;
  const int wid  = tid >> 6;
  const int l4 = lane >> 4, l15 = lane & 15;
  const int bh = blockIdx.y;
  const int qb = blockIdx.x;
  const size_t hoff = (size_t)bh * (S * HD);

  short8 aq0, aq1;
  {
    const u16* qp = Qg + hoff + (size_t)(qb*64 + wid*16 + l15) * HD;
    aq0 = *(const short8*)(qp + 8*l4);
    aq1 = *(const short8*)(qp + 32 + 8*l4);
  }

  float mr[4], lr[4];
  f32x4 oacc[4];
  #pragma unroll
  for (int r=0;r<4;r++){ mr[r] = -1e30f; lr[r] = 0.f; }
  #pragma unroll
  for (int hb=0;hb<4;hb++) oacc[hb] = (f32x4){0.f,0.f,0.f,0.f};

  const char* Kb = (const char*)(Kg + hoff);
  const char* Vb = (const char*)(Vg + hoff);
  char* KsB = (char*)Ks;
  char* VsB = (char*)Vs;
  char* PsB = (char*)Ps + wid*2048;

  int ldsu[2], lb[2], srcK[2];
  #pragma unroll
  for (int p=0;p<2;p++){
    ldsu[p] = wid*2048 + p*1024;                 // wave-uniform LDS base
    lb[p]   = ldsu[p] + lane*16;                 // lane chunk
    int row = lb[p] >> 7, cc = (lb[p] >> 4) & 7; // 128B rows, 16B chunks
    srcK[p] = (row << 7) + ((cc ^ (row & 7)) << 4); // pre-swizzled source
  }

  for (int kt = 0; kt < S/64; ++kt){
    const char* Ksrc = Kb + kt*8192;   // 64x64 bf16 tile is contiguous
    const char* Vsrc = Vb + kt*8192;
    #pragma unroll
    for (int p=0;p<2;p++){
      gload_lds16(Ksrc + srcK[p], KsB + ldsu[p]);
      gload_lds16(Vsrc + lb[p],   VsB + ldsu[p]);
    }
    __syncthreads();

    // S = Q K^T (A=Q rows, B cols = kv rows of K)
    f32x4 sacc[4];
    #pragma unroll
    for (int nb=0;nb<4;nb++){
      const int krow = nb*16 + l15;
      const int swz  = l15 & 7;
      short8 b0 = *(const short8*)(KsB + krow*128 + ((l4 ^ swz) << 4));
      short8 b1 = *(const short8*)(KsB + krow*128 + (((4 + l4) ^ swz) << 4));
      f32x4 zz = (f32x4){0.f,0.f,0.f,0.f};
      zz = __builtin_amdgcn_mfma_f32_16x16x32_bf16(aq0, b0, zz, 0,0,0);
      zz = __builtin_amdgcn_mfma_f32_16x16x32_bf16(aq1, b1, zz, 0,0,0);
      sacc[nb] = zz;
    }
    #pragma unroll
    for (int nb=0;nb<4;nb++)
      #pragma unroll
      for (int r=0;r<4;r++) sacc[nb][r] *= 0.125f;   // 1/sqrt(64)

    // online softmax (rows live on fixed 16-lane groups)
    float mnew[4], alpha[4];
    #pragma unroll
    for (int r=0;r<4;r++){
      float t = fmaxf(fmaxf(sacc[0][r], sacc[1][r]), fmaxf(sacc[2][r], sacc[3][r]));
      t = fmaxf(t, __shfl_xor(t, 1, 16));
      t = fmaxf(t, __shfl_xor(t, 2, 16));
      t = fmaxf(t, __shfl_xor(t, 4, 16));
      t = fmaxf(t, __shfl_xor(t, 8, 16));
      mnew[r]  = fmaxf(mr[r], t);
      alpha[r] = __expf(mr[r] - mnew[r]);
      mr[r]    = mnew[r];
    }
    #pragma unroll
    for (int r=0;r<4;r++){
      float rs = 0.f;
      #pragma unroll
      for (int nb=0;nb<4;nb++){
        float p = __expf(sacc[nb][r] - mnew[r]);
        sacc[nb][r] = p;
        rs += p;
      }
      rs += __shfl_xor(rs, 1, 16);
      rs += __shfl_xor(rs, 2, 16);
      rs += __shfl_xor(rs, 4, 16);
      rs += __shfl_xor(rs, 8, 16);
      lr[r] = lr[r]*alpha[r] + rs;
      #pragma unroll
      for (int hb=0;hb<4;hb++) oacc[hb][r] *= alpha[r];
    }

    // P (16x64, bf16) -> per-wave LDS, row-XOR-swizzled
    #pragma unroll
    for (int r=0;r<4;r++){
      const int prow = 4*l4 + r;
      const int rsw  = (prow & 7) << 4;
      #pragma unroll
      for (int nb=0;nb<4;nb++){
        const int cby = (nb*16 + l15) * 2;
        *(u16*)(PsB + prow*128 + (cby ^ rsw)) = f2bf(sacc[nb][r]);
      }
    }

    // O += P V
    #pragma unroll
    for (int ks=0;ks<2;ks++){
      const int swz = l15 & 7;
      short8 ap = *(const short8*)(PsB + l15*128 + (((ks*4 + l4) ^ swz) << 4));
      #pragma unroll
      for (int hb=0;hb<4;hb++){
        short8 bv;
        #pragma unroll
        for (int j=0;j<8;j++)
          bv[j] = (short)Vs[(ks*32 + 8*l4 + j)*64 + hb*16 + l15];
        oacc[hb] = __builtin_amdgcn_mfma_f32_16x16x32_bf16(ap, bv, oacc[hb], 0,0,0);
      }
    }
    __syncthreads();
  }

  const int b = bh >> 4, h = bh & 15;
  #pragma unroll
  for (int hb=0;hb<4;hb++){
    #pragma unroll
    for (int r=0;r<4;r++){
      const int si = qb*64 + wid*16 + 4*l4 + r;
      const float v = oacc[hb][r] / lr[r];
      Og[(((size_t)(b*S + si))*H + h)*HD + hb*16 + l15] = f2bf(v);
    }
  }
}

extern "C" void kernel_launch(void* const* d_in, const int* in_sizes, int n_in,
                              void* d_out, int out_size, void* d_ws, size_t ws_size,
                              hipStream_t stream) {
  const float* x  = (const float*)d_in[0];
  const float* Wq = (const float*)d_in[1];
  const float* bq = (const float*)d_in[2];
  const float* Wk = (const float*)d_in[3];
  const float* bk = (const float*)d_in[4];
  const float* Wv = (const float*)d_in[5];
  const float* bv = (const float*)d_in[6];
  const float* Wo = (const float*)d_in[7];
  const float* bo = (const float*)d_in[8];

  char* ws = (char*)d_ws;
  // layout (bytes): xb 0..8M | Wb 8M..16M (Wq,Wk,Wv,Wo) | Q 16M | K 24M | V 32M | AO 40M..48M
  u16* xb  = (u16*)(ws);
  u16* Wb  = (u16*)(ws + (size_t)8*1024*1024);
  u16* QKV = (u16*)(ws + (size_t)16*1024*1024);
  u16* AO  = (u16*)(ws + (size_t)40*1024*1024);
  float* out = (float*)d_out;

  cast_f32_bf16<<<4096, 256, 0, stream>>>(x,  xb, 4194304);
  cast_f32_bf16<<<1024, 256, 0, stream>>>(Wq, Wb,            1048576);
  cast_f32_bf16<<<1024, 256, 0, stream>>>(Wk, Wb + 1048576,  1048576);
  cast_f32_bf16<<<1024, 256, 0, stream>>>(Wv, Wb + 2097152,  1048576);
  cast_f32_bf16<<<1024, 256, 0, stream>>>(Wo, Wb + 3145728,  1048576);

  dim3 g1(8, 32, 3);
  gemm_bt<0><<<g1, 256, 0, stream>>>(xb, Wb, bq, bk, bv, QKV, nullptr);

  dim3 g2(32, 32, 1);
  attn_fwd<<<g2, 256, 0, stream>>>(QKV, QKV + 4194304, QKV + 2*4194304, AO);

  dim3 g3(8, 32, 1);
  gemm_bt<1><<<g3, 256, 0, stream>>>(AO, Wb + 3145728, bo, bo, bo, nullptr, out);
}

// Round 2
// 204.838 us; speedup vs baseline: 1.0761x; 1.0761x over previous
//
#include <hip/hip_runtime.h>
#include <hip/hip_bf16.h>
#include <stdint.h>

typedef __attribute__((ext_vector_type(8))) short short8;
typedef __attribute__((ext_vector_type(4))) float f32x4;
typedef unsigned short u16;
typedef unsigned int u32;

static constexpr int S = 2048;
static constexpr int H = 16;
static constexpr int HD = 64;

__device__ __forceinline__ u16 f2bf(float f){
  union { float f; u32 u; } x; x.f = f;
  u32 r = x.u + 0x7fffu + ((x.u >> 16) & 1u);
  return (u16)(r >> 16);
}

__global__ __launch_bounds__(256) void cast_f32_bf16(const float* __restrict__ src,
                                                     u16* __restrict__ dst, int n){
  int i = (blockIdx.x * 256 + threadIdx.x) * 4;
  if (i >= n) return;
  float4 v = *(const float4*)(src + i);
  ushort4 o;
  o.x = f2bf(v.x); o.y = f2bf(v.y); o.z = f2bf(v.z); o.w = f2bf(v.w);
  *(ushort4*)(dst + i) = o;
}

__device__ __forceinline__ void gload_lds16(const void* g, void* lds_uniform){
  __builtin_amdgcn_global_load_lds(
      (const __attribute__((address_space(1))) u32*)g,
      (__attribute__((address_space(3))) u32*)lds_uniform,
      16, 0, 0);
}

// C = A * W^T + bias.  A: [M x 1024] bf16 row-major. W: [1024 x 1024] bf16 (out,in).
// EPI==0: QKV. z=0 (Q), z=1 (K) -> bf16 [B,H,S,HD]; z=2 (V) -> bf16 [B,H,HD,S] (transposed).
// EPI==1: write fp32 [M,1024].
template<int EPI>
__global__ __launch_bounds__(256) void gemm_bt(const u16* __restrict__ A,
                                               const u16* __restrict__ Wall,
                                               const float* __restrict__ b0p,
                                               const float* __restrict__ b1p,
                                               const float* __restrict__ b2p,
                                               u16* __restrict__ obf,
                                               float* __restrict__ ofp){
  __shared__ __align__(16) u16 As[128*32];
  __shared__ __align__(16) u16 Bs[128*32];

  const int tid  = threadIdx.x;
  const int lane = tid & 63;
  const int wid  = tid >> 6;
  const int wm = wid >> 1, wn = wid & 1;
  const int l4 = lane >> 4, l15 = lane & 15;
  const int m0 = blockIdx.y * 128;
  const int n0 = blockIdx.x * 128;
  const int z  = blockIdx.z;

  const u16* Bw = Wall + (size_t)z * (1024*1024);
  const float* bias = (z == 0) ? b0p : ((z == 1) ? b1p : b2p);

  f32x4 acc[4][4];
  #pragma unroll
  for (int m=0;m<4;m++)
    #pragma unroll
    for (int n=0;n<4;n++) acc[m][n] = (f32x4){0.f,0.f,0.f,0.f};

  const char* Ab = (const char*)A  + (size_t)m0 * 2048;   // row stride = 1024*2B
  const char* Bb = (const char*)Bw + (size_t)n0 * 2048;
  char* AsB = (char*)As;
  char* BsB = (char*)Bs;

  int ldsu[2], row_[2], col_[2];
  #pragma unroll
  for (int p=0;p<2;p++){
    ldsu[p] = wid*1024 + p*4096;          // wave-uniform LDS byte base
    int b = ldsu[p] + lane*16;            // this lane's 16B chunk
    row_[p] = b >> 6;                     // tile row (64B per row: 32 bf16)
    col_[p] = b & 63;                     // byte within row
  }

  for (int kt = 0; kt < 32; ++kt){
    const int kb = kt * 64;               // K byte offset
    #pragma unroll
    for (int p=0;p<2;p++){
      gload_lds16(Ab + (size_t)row_[p]*2048 + kb + col_[p], AsB + ldsu[p]);
      gload_lds16(Bb + (size_t)row_[p]*2048 + kb + col_[p], BsB + ldsu[p]);
    }
    __syncthreads();

    short8 af[4], bfr[4];
    const int kcol = 8 * l4;
    #pragma unroll
    for (int m=0;m<4;m++)
      af[m] = *(const short8*)&As[(wm*64 + m*16 + l15)*32 + kcol];
    #pragma unroll
    for (int n=0;n<4;n++)
      bfr[n] = *(const short8*)&Bs[(wn*64 + n*16 + l15)*32 + kcol];

    #pragma unroll
    for (int m=0;m<4;m++)
      #pragma unroll
      for (int n=0;n<4;n++)
        acc[m][n] = __builtin_amdgcn_mfma_f32_16x16x32_bf16(af[m], bfr[n], acc[m][n], 0,0,0);

    __syncthreads();
  }

  #pragma unroll
  for (int m=0;m<4;m++){
    const int rgb = m0 + wm*64 + m*16 + 4*l4;
    #pragma unroll
    for (int n=0;n<4;n++){
      const int cg = n0 + wn*64 + n*16 + l15;
      const float bb = bias[cg];
      if (EPI == 0){
        const int bi = rgb >> 11, si = rgb & 2047;   // 4 rows share bi (rgb % 4 == 0)
        const int hi = cg >> 6,  hd = cg & 63;
        if (z == 2){
          // V transposed: [B,H,HD,S], pack 4 consecutive tokens -> 8B store
          u16* outz = obf + (size_t)2 * 4194304u;
          ushort4 o;
          o.x = f2bf(acc[m][n][0] + bb);
          o.y = f2bf(acc[m][n][1] + bb);
          o.z = f2bf(acc[m][n][2] + bb);
          o.w = f2bf(acc[m][n][3] + bb);
          *(ushort4*)&outz[(((size_t)(bi*16 + hi))*64 + hd)*2048 + si] = o;
        } else {
          u16* outz = obf + (size_t)z * 4194304u;
          #pragma unroll
          for (int r=0;r<4;r++)
            outz[(((size_t)(bi*16 + hi))*2048 + (si + r))*64 + hd] = f2bf(acc[m][n][r] + bb);
        }
      } else {
        #pragma unroll
        for (int r=0;r<4;r++)
          ofp[(size_t)(rgb + r)*1024 + cg] = acc[m][n][r] + bb;
      }
    }
  }
}

// Flash attention. Q,K: bf16 [B,H,S,HD]. Vt: bf16 [B,H,HD,S]. Out: bf16 [B,S,H,HD].
// grid = (S/64, B*H), 256 threads (4 waves x 16 q-rows).
__global__ __launch_bounds__(256) void attn_fwd(const u16* __restrict__ Qg,
                                                const u16* __restrict__ Kg,
                                                const u16* __restrict__ Vtg,
                                                u16* __restrict__ Og){
  __shared__ __align__(16) u16 Ks[64*64];      // XOR-swizzled rows (kv x hd)
  __shared__ __align__(16) u16 Vs[64*64];      // XOR-swizzled rows (hd x kv)
  __shared__ __align__(16) u16 Ps[4*16*64];    // per-wave P, swizzled

  const int tid  = threadIdx.x;
  const int lane = tid & 63;
  const int wid  = tid >> 6;
  const int l4 = lane >> 4, l15 = lane & 15;
  const int bh = blockIdx.y;
  const int qb = blockIdx.x;
  const size_t hoff = (size_t)bh * (S * HD);   // same flat offset for [S,HD] and [HD,S]

  short8 aq0, aq1;
  {
    const u16* qp = Qg + hoff + (size_t)(qb*64 + wid*16 + l15) * HD;
    aq0 = *(const short8*)(qp + 8*l4);
    aq1 = *(const short8*)(qp + 32 + 8*l4);
  }

  float mr[4], lr[4];
  f32x4 oacc[4];
  #pragma unroll
  for (int r=0;r<4;r++){ mr[r] = -1e30f; lr[r] = 0.f; }
  #pragma unroll
  for (int hb=0;hb<4;hb++) oacc[hb] = (f32x4){0.f,0.f,0.f,0.f};

  const char* Kb = (const char*)(Kg  + hoff);
  const char* Vb = (const char*)(Vtg + hoff);
  char* KsB = (char*)Ks;
  char* VsB = (char*)Vs;
  char* PsB = (char*)Ps + wid*2048;

  int ldsu[2], srcK[2], srcV[2];
  #pragma unroll
  for (int p=0;p<2;p++){
    ldsu[p] = wid*2048 + p*1024;                 // wave-uniform LDS base (byte, 0..8191)
    int b   = ldsu[p] + lane*16;                 // dest byte in tile
    int row = b >> 7, cc = (b >> 4) & 7;         // 128B rows, 16B chunks
    int ccs = cc ^ (row & 7);                    // pre-swizzled chunk (inverse == same XOR)
    srcK[p] = row*128  + (ccs << 4);             // K tile: global row stride 128B, tile contiguous
    srcV[p] = row*4096 + (ccs << 4);             // Vt: global row stride S*2 = 4096B
  }

  for (int kt = 0; kt < S/64; ++kt){
    const char* Ksrc = Kb + kt*8192;   // 64x64 bf16 K tile contiguous
    const char* Vsrc = Vb + kt*128;    // Vt tile: 64 rows (hd), 128B each, stride 4096B
    #pragma unroll
    for (int p=0;p<2;p++){
      gload_lds16(Ksrc + srcK[p], KsB + ldsu[p]);
      gload_lds16(Vsrc + srcV[p], VsB + ldsu[p]);
    }
    __syncthreads();

    // S = Q K^T (A=Q rows, B cols = kv rows of K)
    f32x4 sacc[4];
    const int swz = l15 & 7;
    #pragma unroll
    for (int nb=0;nb<4;nb++){
      const int krow = nb*16 + l15;
      short8 b0 = *(const short8*)(KsB + krow*128 + ((l4 ^ swz) << 4));
      short8 b1 = *(const short8*)(KsB + krow*128 + (((4 + l4) ^ swz) << 4));
      f32x4 zz = (f32x4){0.f,0.f,0.f,0.f};
      zz = __builtin_amdgcn_mfma_f32_16x16x32_bf16(aq0, b0, zz, 0,0,0);
      zz = __builtin_amdgcn_mfma_f32_16x16x32_bf16(aq1, b1, zz, 0,0,0);
      sacc[nb] = zz;
    }
    #pragma unroll
    for (int nb=0;nb<4;nb++)
      #pragma unroll
      for (int r=0;r<4;r++) sacc[nb][r] *= 0.125f;   // 1/sqrt(64)

    // online softmax (rows live on fixed 16-lane groups)
    float mnew[4], alpha[4];
    #pragma unroll
    for (int r=0;r<4;r++){
      float t = fmaxf(fmaxf(sacc[0][r], sacc[1][r]), fmaxf(sacc[2][r], sacc[3][r]));
      t = fmaxf(t, __shfl_xor(t, 1, 16));
      t = fmaxf(t, __shfl_xor(t, 2, 16));
      t = fmaxf(t, __shfl_xor(t, 4, 16));
      t = fmaxf(t, __shfl_xor(t, 8, 16));
      mnew[r]  = fmaxf(mr[r], t);
      alpha[r] = __expf(mr[r] - mnew[r]);
      mr[r]    = mnew[r];
    }
    #pragma unroll
    for (int r=0;r<4;r++){
      float rs = 0.f;
      #pragma unroll
      for (int nb=0;nb<4;nb++){
        float p = __expf(sacc[nb][r] - mnew[r]);
        sacc[nb][r] = p;
        rs += p;
      }
      rs += __shfl_xor(rs, 1, 16);
      rs += __shfl_xor(rs, 2, 16);
      rs += __shfl_xor(rs, 4, 16);
      rs += __shfl_xor(rs, 8, 16);
      lr[r] = lr[r]*alpha[r] + rs;
      #pragma unroll
      for (int hb=0;hb<4;hb++) oacc[hb][r] *= alpha[r];
    }

    // P (16x64, bf16) -> per-wave LDS, row-XOR-swizzled
    #pragma unroll
    for (int r=0;r<4;r++){
      const int prow = 4*l4 + r;
      const int rsw  = (prow & 7) << 4;
      #pragma unroll
      for (int nb=0;nb<4;nb++){
        const int cby = (nb*16 + l15) * 2;
        *(u16*)(PsB + prow*128 + (cby ^ rsw)) = f2bf(sacc[nb][r]);
      }
    }

    // O += P V  (B-fragment: 8 consecutive kv for fixed hd -> contiguous swizzled read)
    #pragma unroll
    for (int ks=0;ks<2;ks++){
      short8 ap = *(const short8*)(PsB + l15*128 + (((ks*4 + l4) ^ swz) << 4));
      #pragma unroll
      for (int hb=0;hb<4;hb++){
        const int vrow = hb*16 + l15;           // vrow & 7 == swz
        short8 bv = *(const short8*)(VsB + vrow*128 + (((ks*4 + l4) ^ swz) << 4));
        oacc[hb] = __builtin_amdgcn_mfma_f32_16x16x32_bf16(ap, bv, oacc[hb], 0,0,0);
      }
    }
    __syncthreads();
  }

  const int b = bh >> 4, h = bh & 15;
  #pragma unroll
  for (int hb=0;hb<4;hb++){
    #pragma unroll
    for (int r=0;r<4;r++){
      const int si = qb*64 + wid*16 + 4*l4 + r;
      const float v = oacc[hb][r] / lr[r];
      Og[(((size_t)(b*S + si))*H + h)*HD + hb*16 + l15] = f2bf(v);
    }
  }
}

extern "C" void kernel_launch(void* const* d_in, const int* in_sizes, int n_in,
                              void* d_out, int out_size, void* d_ws, size_t ws_size,
                              hipStream_t stream) {
  const float* x  = (const float*)d_in[0];
  const float* Wq = (const float*)d_in[1];
  const float* bq = (const float*)d_in[2];
  const float* Wk = (const float*)d_in[3];
  const float* bk = (const float*)d_in[4];
  const float* Wv = (const float*)d_in[5];
  const float* bv = (const float*)d_in[6];
  const float* Wo = (const float*)d_in[7];
  const float* bo = (const float*)d_in[8];

  char* ws = (char*)d_ws;
  // layout (bytes): xb 0..8M | Wb 8M..16M (Wq,Wk,Wv,Wo) | Q 16M | K 24M | Vt 32M | AO 40M..48M
  u16* xb  = (u16*)(ws);
  u16* Wb  = (u16*)(ws + (size_t)8*1024*1024);
  u16* QKV = (u16*)(ws + (size_t)16*1024*1024);
  u16* AO  = (u16*)(ws + (size_t)40*1024*1024);
  float* out = (float*)d_out;

  cast_f32_bf16<<<4096, 256, 0, stream>>>(x,  xb, 4194304);
  cast_f32_bf16<<<1024, 256, 0, stream>>>(Wq, Wb,            1048576);
  cast_f32_bf16<<<1024, 256, 0, stream>>>(Wk, Wb + 1048576,  1048576);
  cast_f32_bf16<<<1024, 256, 0, stream>>>(Wv, Wb + 2097152,  1048576);
  cast_f32_bf16<<<1024, 256, 0, stream>>>(Wo, Wb + 3145728,  1048576);

  dim3 g1(8, 32, 3);
  gemm_bt<0><<<g1, 256, 0, stream>>>(xb, Wb, bq, bk, bv, QKV, nullptr);

  dim3 g2(32, 32, 1);
  attn_fwd<<<g2, 256, 0, stream>>>(QKV, QKV + 4194304, QKV + 2*4194304, AO);

  dim3 g3(8, 32, 1);
  gemm_bt<1><<<g3, 256, 0, stream>>>(AO, Wb + 3145728, bo, bo, bo, nullptr, out);
}

// Round 4
// 163.620 us; speedup vs baseline: 1.3471x; 1.2519x over previous
//
#include <hip/hip_runtime.h>
#include <hip/hip_bf16.h>
#include <stdint.h>

typedef __attribute__((ext_vector_type(8))) short short8;
typedef __attribute__((ext_vector_type(4))) float f32x4;
typedef unsigned short u16;
typedef unsigned int u32;

static constexpr int S = 2048;
static constexpr int H = 16;
static constexpr int HD = 64;

__device__ __forceinline__ float fast_exp2(float x){
  return __builtin_amdgcn_exp2f(x);
}

__device__ __forceinline__ u16 f2bf(float f){
  union { float f; u32 u; } x; x.f = f;
  u32 r = x.u + 0x7fffu + ((x.u >> 16) & 1u);
  return (u16)(r >> 16);
}

__global__ __launch_bounds__(256) void cast_f32_bf16(const float* __restrict__ src,
                                                     u16* __restrict__ dst, int n){
  int i = (blockIdx.x * 256 + threadIdx.x) * 4;
  if (i >= n) return;
  float4 v = *(const float4*)(src + i);
  ushort4 o;
  o.x = f2bf(v.x); o.y = f2bf(v.y); o.z = f2bf(v.z); o.w = f2bf(v.w);
  *(ushort4*)(dst + i) = o;
}

__device__ __forceinline__ void gload_lds16(const void* g, void* lds_uniform){
  __builtin_amdgcn_global_load_lds(
      (const __attribute__((address_space(1))) u32*)g,
      (__attribute__((address_space(3))) u32*)lds_uniform,
      16, 0, 0);
}

// C = A * W^T + bias.  A: [M x 1024] bf16 row-major. W: [1024 x 1024] bf16 (out,in).
// EPI==0: QKV. z=0 (Q, pre-scaled by 0.125*log2e) , z=1 (K) -> bf16 [B,H,S,HD];
//         z=2 (V) -> bf16 [B,H,HD,S] (transposed).
// EPI==1: write fp32 [M,1024].
template<int EPI>
__global__ __launch_bounds__(256) void gemm_bt(const u16* __restrict__ A,
                                               const u16* __restrict__ Wall,
                                               const float* __restrict__ b0p,
                                               const float* __restrict__ b1p,
                                               const float* __restrict__ b2p,
                                               u16* __restrict__ obf,
                                               float* __restrict__ ofp){
  __shared__ __align__(16) u16 As[128*32];
  __shared__ __align__(16) u16 Bs[128*32];

  const int tid  = threadIdx.x;
  const int lane = tid & 63;
  const int wid  = tid >> 6;
  const int wm = wid >> 1, wn = wid & 1;
  const int l4 = lane >> 4, l15 = lane & 15;
  const int m0 = blockIdx.y * 128;
  const int n0 = blockIdx.x * 128;
  const int z  = blockIdx.z;

  const u16* Bw = Wall + (size_t)z * (1024*1024);
  const float* bias = (z == 0) ? b0p : ((z == 1) ? b1p : b2p);

  f32x4 acc[4][4];
  #pragma unroll
  for (int m=0;m<4;m++)
    #pragma unroll
    for (int n=0;n<4;n++) acc[m][n] = (f32x4){0.f,0.f,0.f,0.f};

  const char* Ab = (const char*)A  + (size_t)m0 * 2048;   // row stride = 1024*2B
  const char* Bb = (const char*)Bw + (size_t)n0 * 2048;
  char* AsB = (char*)As;
  char* BsB = (char*)Bs;

  int ldsu[2], row_[2], col_[2];
  #pragma unroll
  for (int p=0;p<2;p++){
    ldsu[p] = wid*1024 + p*4096;          // wave-uniform LDS byte base
    int b = ldsu[p] + lane*16;            // this lane's 16B chunk
    row_[p] = b >> 6;                     // tile row (64B per row: 32 bf16)
    col_[p] = b & 63;                     // byte within row
  }

  for (int kt = 0; kt < 32; ++kt){
    const int kb = kt * 64;               // K byte offset
    #pragma unroll
    for (int p=0;p<2;p++){
      gload_lds16(Ab + (size_t)row_[p]*2048 + kb + col_[p], AsB + ldsu[p]);
      gload_lds16(Bb + (size_t)row_[p]*2048 + kb + col_[p], BsB + ldsu[p]);
    }
    __syncthreads();

    short8 af[4], bfr[4];
    const int kcol = 8 * l4;
    #pragma unroll
    for (int m=0;m<4;m++)
      af[m] = *(const short8*)&As[(wm*64 + m*16 + l15)*32 + kcol];
    #pragma unroll
    for (int n=0;n<4;n++)
      bfr[n] = *(const short8*)&Bs[(wn*64 + n*16 + l15)*32 + kcol];

    #pragma unroll
    for (int m=0;m<4;m++)
      #pragma unroll
      for (int n=0;n<4;n++)
        acc[m][n] = __builtin_amdgcn_mfma_f32_16x16x32_bf16(af[m], bfr[n], acc[m][n], 0,0,0);

    __syncthreads();
  }

  #pragma unroll
  for (int m=0;m<4;m++){
    const int rgb = m0 + wm*64 + m*16 + 4*l4;
    #pragma unroll
    for (int n=0;n<4;n++){
      const int cg = n0 + wn*64 + n*16 + l15;
      const float bb = bias[cg];
      if (EPI == 0){
        const int bi = rgb >> 11, si = rgb & 2047;   // 4 rows share bi (rgb % 4 == 0)
        const int hi = cg >> 6,  hd = cg & 63;
        if (z == 2){
          // V transposed: [B,H,HD,S], pack 4 consecutive tokens -> 8B store
          u16* outz = obf + (size_t)2 * 4194304u;
          ushort4 o;
          o.x = f2bf(acc[m][n][0] + bb);
          o.y = f2bf(acc[m][n][1] + bb);
          o.z = f2bf(acc[m][n][2] + bb);
          o.w = f2bf(acc[m][n][3] + bb);
          *(ushort4*)&outz[(((size_t)(bi*16 + hi))*64 + hd)*2048 + si] = o;
        } else {
          u16* outz = obf + (size_t)z * 4194304u;
          // Q pre-scaled so attention scores are already in exp2 domain:
          // score*log2e/sqrt(64) folded here.
          const float sc = (z == 0) ? 0.18033688011112042f : 1.0f;
          #pragma unroll
          for (int r=0;r<4;r++)
            outz[(((size_t)(bi*16 + hi))*2048 + (si + r))*64 + hd] =
                f2bf((acc[m][n][r] + bb) * sc);
        }
      } else {
        #pragma unroll
        for (int r=0;r<4;r++)
          ofp[(size_t)(rgb + r)*1024 + cg] = acc[m][n][r] + bb;
      }
    }
  }
}

// Flash attention, swapped-QK^T (P-row lane-local) + 2-phase K/V double-buffer.
// Q,K: bf16 [B,H,S,HD] (Q pre-scaled). Vt: bf16 [B,H,HD,S]. Out: bf16 [B,S,H,HD].
// grid = (S/64, B*H), 256 threads (4 waves x 16 q-rows).
__global__ __launch_bounds__(256) void attn_fwd(const u16* __restrict__ Qg,
                                                const u16* __restrict__ Kg,
                                                const u16* __restrict__ Vtg,
                                                u16* __restrict__ Og){
  __shared__ __align__(16) u16 Ks[2*64*64];    // 2 bufs, XOR-swizzled rows (kv x hd)
  __shared__ __align__(16) u16 Vs[2*64*64];    // 2 bufs, XOR-swizzled rows (hd x kv)
  __shared__ __align__(16) u16 Ps[4*16*64];    // per-wave P, swizzled

  const int tid  = threadIdx.x;
  const int lane = tid & 63;
  const int wid  = tid >> 6;
  const int l4 = lane >> 4, l15 = lane & 15;
  const int swz = l15 & 7;
  const int bh = blockIdx.y;
  const int qb = blockIdx.x;
  const size_t hoff = (size_t)bh * (S * HD);   // same flat offset for [S,HD] and [HD,S]

  short8 aq0, aq1;
  {
    const u16* qp = Qg + hoff + (size_t)(qb*64 + wid*16 + l15) * HD;
    aq0 = *(const short8*)(qp + 8*l4);
    aq1 = *(const short8*)(qp + 32 + 8*l4);
  }

  float mr = -1e30f, lr = 0.f;
  f32x4 oacc[4];
  #pragma unroll
  for (int hb=0;hb<4;hb++) oacc[hb] = (f32x4){0.f,0.f,0.f,0.f};

  const char* Kb = (const char*)(Kg  + hoff);
  const char* Vb = (const char*)(Vtg + hoff);
  char* KsB = (char*)Ks;
  char* VsB = (char*)Vs;
  char* PsB = (char*)Ps + wid*2048;

  int ldsu[2], srcK[2], srcV[2];
  #pragma unroll
  for (int p=0;p<2;p++){
    ldsu[p] = wid*2048 + p*1024;                 // wave-uniform base within one 8KB tile
    int b   = ldsu[p] + lane*16;                 // dest byte in tile
    int row = b >> 7, cc = (b >> 4) & 7;         // 128B rows, 16B chunks
    int ccs = cc ^ (row & 7);                    // pre-swizzled source chunk
    srcK[p] = row*128  + (ccs << 4);             // K tile contiguous (row stride 128B)
    srcV[p] = row*4096 + (ccs << 4);             // Vt row stride S*2 = 4096B
  }

  // prologue: stage tile 0 into buf 0
  {
    const char* Ksrc = Kb;
    const char* Vsrc = Vb;
    #pragma unroll
    for (int p=0;p<2;p++){
      gload_lds16(Ksrc + srcK[p], KsB + ldsu[p]);
      gload_lds16(Vsrc + srcV[p], VsB + ldsu[p]);
    }
  }
  __syncthreads();

  for (int kt = 0; kt < S/64; ++kt){
    const int cur = kt & 1;
    // issue next tile's stage (lands before the end-of-iter barrier drain)
    if (kt + 1 < S/64){
      const int nxt = cur ^ 1;
      const char* Ksrc = Kb + (size_t)(kt+1)*8192;
      const char* Vsrc = Vb + (size_t)(kt+1)*128;
      #pragma unroll
      for (int p=0;p<2;p++){
        gload_lds16(Ksrc + srcK[p], KsB + nxt*8192 + ldsu[p]);
        gload_lds16(Vsrc + srcV[p], VsB + nxt*8192 + ldsu[p]);
      }
    }

    const char* KsC = KsB + cur*8192;
    const char* VsC = VsB + cur*8192;

    // S^T tile: mfma(A=K_frag, B=Q_frag) -> lane holds q = l15, kv = nb*16 + l4*4 + r
    f32x4 sacc[4];
    #pragma unroll
    for (int nb=0;nb<4;nb++){
      const int krow = nb*16 + l15;
      short8 k0 = *(const short8*)(KsC + krow*128 + ((l4 ^ swz) << 4));
      short8 k1 = *(const short8*)(KsC + krow*128 + (((4 + l4) ^ swz) << 4));
      f32x4 zz = (f32x4){0.f,0.f,0.f,0.f};
      zz = __builtin_amdgcn_mfma_f32_16x16x32_bf16(k0, aq0, zz, 0,0,0);
      zz = __builtin_amdgcn_mfma_f32_16x16x32_bf16(k1, aq1, zz, 0,0,0);
      sacc[nb] = zz;
    }

    // in-lane row max (16 values) + 2 cross-group shuffles
    float t0 = fmaxf(fmaxf(sacc[0][0], sacc[0][1]), fmaxf(sacc[0][2], sacc[0][3]));
    float t1 = fmaxf(fmaxf(sacc[1][0], sacc[1][1]), fmaxf(sacc[1][2], sacc[1][3]));
    float t2 = fmaxf(fmaxf(sacc[2][0], sacc[2][1]), fmaxf(sacc[2][2], sacc[2][3]));
    float t3 = fmaxf(fmaxf(sacc[3][0], sacc[3][1]), fmaxf(sacc[3][2], sacc[3][3]));
    float t = fmaxf(fmaxf(t0, t1), fmaxf(t2, t3));
    t = fmaxf(t, __shfl_xor(t, 16, 64));
    t = fmaxf(t, __shfl_xor(t, 32, 64));

    // defer-max: only rescale when tile max grew past THR=8 (exp2 domain -> P <= 256)
    if (!__all(t <= mr + 8.f)){
      const float mnew = fmaxf(mr, t);
      const float alpha = fast_exp2(mr - mnew);
      mr = mnew;
      lr *= alpha;
      float af[4];
      #pragma unroll
      for (int r=0;r<4;r++) af[r] = __shfl(alpha, 4*l4 + r, 64);
      #pragma unroll
      for (int hb=0;hb<4;hb++)
        #pragma unroll
        for (int r=0;r<4;r++) oacc[hb][r] *= af[r];
    }

    float rs = 0.f;
    #pragma unroll
    for (int nb=0;nb<4;nb++)
      #pragma unroll
      for (int r=0;r<4;r++){
        float p = fast_exp2(sacc[nb][r] - mr);
        sacc[nb][r] = p;
        rs += p;
      }
    rs += __shfl_xor(rs, 16, 64);
    rs += __shfl_xor(rs, 32, 64);
    lr += rs;

    // P row (q=l15) -> per-wave LDS, 4x ds_write_b64, swizzled to match A-frag read
    #pragma unroll
    for (int nb=0;nb<4;nb++){
      u32 lo = (u32)f2bf(sacc[nb][0]) | ((u32)f2bf(sacc[nb][1]) << 16);
      u32 hi = (u32)f2bf(sacc[nb][2]) | ((u32)f2bf(sacc[nb][3]) << 16);
      const int chunk = nb*2 + (l4 >> 1);
      const int sub   = (l4 & 1) * 8;
      *(uint2*)(PsB + l15*128 + ((chunk ^ swz) << 4) + sub) = make_uint2(lo, hi);
    }

    // O += P V
    #pragma unroll
    for (int ks=0;ks<2;ks++){
      short8 ap = *(const short8*)(PsB + l15*128 + (((ks*4 + l4) ^ swz) << 4));
      #pragma unroll
      for (int hb=0;hb<4;hb++){
        const int vrow = hb*16 + l15;
        short8 bv = *(const short8*)(VsC + vrow*128 + (((ks*4 + l4) ^ swz) << 4));
        oacc[hb] = __builtin_amdgcn_mfma_f32_16x16x32_bf16(ap, bv, oacc[hb], 0,0,0);
      }
    }
    __syncthreads();   // drains stage(kt+1) vmem + orders buffer reuse
  }

  // final: broadcast per-row sums to oacc lanes, normalize, store
  float inv[4];
  #pragma unroll
  for (int r=0;r<4;r++){
    float lq = __shfl(lr, 4*l4 + r, 64);
    inv[r] = 1.0f / lq;
  }
  const int b = bh >> 4, h = bh & 15;
  #pragma unroll
  for (int hb=0;hb<4;hb++){
    #pragma unroll
    for (int r=0;r<4;r++){
      const int si = qb*64 + wid*16 + 4*l4 + r;
      const float v = oacc[hb][r] * inv[r];
      Og[(((size_t)(b*S + si))*H + h)*HD + hb*16 + l15] = f2bf(v);
    }
  }
}

extern "C" void kernel_launch(void* const* d_in, const int* in_sizes, int n_in,
                              void* d_out, int out_size, void* d_ws, size_t ws_size,
                              hipStream_t stream) {
  const float* x  = (const float*)d_in[0];
  const float* Wq = (const float*)d_in[1];
  const float* bq = (const float*)d_in[2];
  const float* Wk = (const float*)d_in[3];
  const float* bk = (const float*)d_in[4];
  const float* Wv = (const float*)d_in[5];
  const float* bv = (const float*)d_in[6];
  const float* Wo = (const float*)d_in[7];
  const float* bo = (const float*)d_in[8];

  char* ws = (char*)d_ws;
  // layout (bytes): xb 0..8M | Wb 8M..16M (Wq,Wk,Wv,Wo) | Q 16M | K 24M | Vt 32M | AO 40M..48M
  u16* xb  = (u16*)(ws);
  u16* Wb  = (u16*)(ws + (size_t)8*1024*1024);
  u16* QKV = (u16*)(ws + (size_t)16*1024*1024);
  u16* AO  = (u16*)(ws + (size_t)40*1024*1024);
  float* out = (float*)d_out;

  cast_f32_bf16<<<4096, 256, 0, stream>>>(x,  xb, 4194304);
  cast_f32_bf16<<<1024, 256, 0, stream>>>(Wq, Wb,            1048576);
  cast_f32_bf16<<<1024, 256, 0, stream>>>(Wk, Wb + 1048576,  1048576);
  cast_f32_bf16<<<1024, 256, 0, stream>>>(Wv, Wb + 2097152,  1048576);
  cast_f32_bf16<<<1024, 256, 0, stream>>>(Wo, Wb + 3145728,  1048576);

  dim3 g1(8, 32, 3);
  gemm_bt<0><<<g1, 256, 0, stream>>>(xb, Wb, bq, bk, bv, QKV, nullptr);

  dim3 g2(32, 32, 1);
  attn_fwd<<<g2, 256, 0, stream>>>(QKV, QKV + 4194304, QKV + 2*4194304, AO);

  dim3 g3(8, 32, 1);
  gemm_bt<1><<<g3, 256, 0, stream>>>(AO, Wb + 3145728, bo, bo, bo, nullptr, out);
}

// Round 5
// 145.017 us; speedup vs baseline: 1.5200x; 1.1283x over previous
//
#include <hip/hip_runtime.h>
#include <hip/hip_bf16.h>
#include <stdint.h>

typedef __attribute__((ext_vector_type(8))) short short8;
typedef __attribute__((ext_vector_type(4))) float f32x4;
typedef unsigned short u16;
typedef unsigned int u32;

static constexpr int S = 2048;
static constexpr int H = 16;
static constexpr int HD = 64;

__device__ __forceinline__ float fast_exp2(float x){
  return __builtin_amdgcn_exp2f(x);
}

__device__ __forceinline__ u16 f2bf(float f){
  union { float f; u32 u; } x; x.f = f;
  u32 r = x.u + 0x7fffu + ((x.u >> 16) & 1u);
  return (u16)(r >> 16);
}

// packed RNE f32x2 -> bf16x2 (no builtin on gfx950; single VALU op)
__device__ __forceinline__ u32 cvt_pk_bf16(float lo, float hi){
  u32 r;
  asm("v_cvt_pk_bf16_f32 %0, %1, %2" : "=v"(r) : "v"(lo), "v"(hi));
  return r;
}

__global__ __launch_bounds__(256) void cast_f32_bf16(const float* __restrict__ src,
                                                     u16* __restrict__ dst, int n){
  int i = (blockIdx.x * 256 + threadIdx.x) * 4;
  if (i >= n) return;
  float4 v = *(const float4*)(src + i);
  ushort4 o;
  o.x = f2bf(v.x); o.y = f2bf(v.y); o.z = f2bf(v.z); o.w = f2bf(v.w);
  *(ushort4*)(dst + i) = o;
}

// 4 weight matrices (1M elems each) -> contiguous bf16 dst
__global__ __launch_bounds__(256) void cast_w4(const float* __restrict__ a,
                                               const float* __restrict__ b,
                                               const float* __restrict__ c,
                                               const float* __restrict__ d,
                                               u16* __restrict__ dst){
  int i = (blockIdx.x * 256 + threadIdx.x) * 4;
  const float* s = (i < 2097152) ? ((i < 1048576) ? a : b)
                                 : ((i < 3145728) ? c : d);
  float4 v = *(const float4*)(s + (i & 1048575));
  ushort4 o;
  o.x = f2bf(v.x); o.y = f2bf(v.y); o.z = f2bf(v.z); o.w = f2bf(v.w);
  *(ushort4*)(dst + i) = o;
}

__device__ __forceinline__ void gload_lds16(const void* g, void* lds_uniform){
  __builtin_amdgcn_global_load_lds(
      (const __attribute__((address_space(1))) u32*)g,
      (__attribute__((address_space(3))) u32*)lds_uniform,
      16, 0, 0);
}

// C = A * W^T + bias.  A: [M x 1024] bf16 row-major. W: [1024 x 1024] bf16 (out,in).
// EPI==0: QKV. z=0 (Q, pre-scaled by 0.125*log2e) , z=1 (K) -> bf16 [B,H,S,HD];
//         z=2 (V) -> bf16 [B,H,HD,S] (transposed).
// EPI==1: write fp32 [M,1024].
template<int EPI>
__global__ __launch_bounds__(256) void gemm_bt(const u16* __restrict__ A,
                                               const u16* __restrict__ Wall,
                                               const float* __restrict__ b0p,
                                               const float* __restrict__ b1p,
                                               const float* __restrict__ b2p,
                                               u16* __restrict__ obf,
                                               float* __restrict__ ofp){
  __shared__ __align__(16) u16 As[128*32];
  __shared__ __align__(16) u16 Bs[128*32];

  const int tid  = threadIdx.x;
  const int lane = tid & 63;
  const int wid  = tid >> 6;
  const int wm = wid >> 1, wn = wid & 1;
  const int l4 = lane >> 4, l15 = lane & 15;
  const int m0 = blockIdx.y * 128;
  const int n0 = blockIdx.x * 128;
  const int z  = blockIdx.z;

  const u16* Bw = Wall + (size_t)z * (1024*1024);
  const float* bias = (z == 0) ? b0p : ((z == 1) ? b1p : b2p);

  f32x4 acc[4][4];
  #pragma unroll
  for (int m=0;m<4;m++)
    #pragma unroll
    for (int n=0;n<4;n++) acc[m][n] = (f32x4){0.f,0.f,0.f,0.f};

  const char* Ab = (const char*)A  + (size_t)m0 * 2048;   // row stride = 1024*2B
  const char* Bb = (const char*)Bw + (size_t)n0 * 2048;
  char* AsB = (char*)As;
  char* BsB = (char*)Bs;

  int ldsu[2], row_[2], col_[2];
  #pragma unroll
  for (int p=0;p<2;p++){
    ldsu[p] = wid*1024 + p*4096;          // wave-uniform LDS byte base
    int b = ldsu[p] + lane*16;            // this lane's 16B chunk
    row_[p] = b >> 6;                     // tile row (64B per row: 32 bf16)
    col_[p] = b & 63;                     // byte within row
  }

  for (int kt = 0; kt < 32; ++kt){
    const int kb = kt * 64;               // K byte offset
    #pragma unroll
    for (int p=0;p<2;p++){
      gload_lds16(Ab + (size_t)row_[p]*2048 + kb + col_[p], AsB + ldsu[p]);
      gload_lds16(Bb + (size_t)row_[p]*2048 + kb + col_[p], BsB + ldsu[p]);
    }
    __syncthreads();

    short8 af[4], bfr[4];
    const int kcol = 8 * l4;
    #pragma unroll
    for (int m=0;m<4;m++)
      af[m] = *(const short8*)&As[(wm*64 + m*16 + l15)*32 + kcol];
    #pragma unroll
    for (int n=0;n<4;n++)
      bfr[n] = *(const short8*)&Bs[(wn*64 + n*16 + l15)*32 + kcol];

    #pragma unroll
    for (int m=0;m<4;m++)
      #pragma unroll
      for (int n=0;n<4;n++)
        acc[m][n] = __builtin_amdgcn_mfma_f32_16x16x32_bf16(af[m], bfr[n], acc[m][n], 0,0,0);

    __syncthreads();
  }

  #pragma unroll
  for (int m=0;m<4;m++){
    const int rgb = m0 + wm*64 + m*16 + 4*l4;
    #pragma unroll
    for (int n=0;n<4;n++){
      const int cg = n0 + wn*64 + n*16 + l15;
      const float bb = bias[cg];
      if (EPI == 0){
        const int bi = rgb >> 11, si = rgb & 2047;   // 4 rows share bi (rgb % 4 == 0)
        const int hi = cg >> 6,  hd = cg & 63;
        if (z == 2){
          // V transposed: [B,H,HD,S], pack 4 consecutive tokens -> 8B store
          u16* outz = obf + (size_t)2 * 4194304u;
          ushort4 o;
          o.x = f2bf(acc[m][n][0] + bb);
          o.y = f2bf(acc[m][n][1] + bb);
          o.z = f2bf(acc[m][n][2] + bb);
          o.w = f2bf(acc[m][n][3] + bb);
          *(ushort4*)&outz[(((size_t)(bi*16 + hi))*64 + hd)*2048 + si] = o;
        } else {
          u16* outz = obf + (size_t)z * 4194304u;
          // Q pre-scaled so attention scores are already in exp2 domain:
          // score*log2e/sqrt(64) folded here.
          const float sc = (z == 0) ? 0.18033688011112042f : 1.0f;
          #pragma unroll
          for (int r=0;r<4;r++)
            outz[(((size_t)(bi*16 + hi))*2048 + (si + r))*64 + hd] =
                f2bf((acc[m][n][r] + bb) * sc);
        }
      } else {
        #pragma unroll
        for (int r=0;r<4;r++)
          ofp[(size_t)(rgb + r)*1024 + cg] = acc[m][n][r] + bb;
      }
    }
  }
}

// Flash attention, swapped-QK^T (P-row lane-local) + 2-phase K/V double-buffer.
// Q,K: bf16 [B,H,S,HD] (Q pre-scaled). Vt: bf16 [B,H,HD,S]. Out: bf16 [B,S,H,HD].
// grid = (S/64, B*H), 256 threads (4 waves x 16 q-rows).
__global__ __launch_bounds__(256) void attn_fwd(const u16* __restrict__ Qg,
                                                const u16* __restrict__ Kg,
                                                const u16* __restrict__ Vtg,
                                                u16* __restrict__ Og){
  __shared__ __align__(16) u16 Ks[2*64*64];    // 2 bufs, XOR-swizzled rows (kv x hd)
  __shared__ __align__(16) u16 Vs[2*64*64];    // 2 bufs, XOR-swizzled rows (hd x kv)
  __shared__ __align__(16) u16 Ps[4*16*64];    // per-wave P, swizzled

  const int tid  = threadIdx.x;
  const int lane = tid & 63;
  const int wid  = tid >> 6;
  const int l4 = lane >> 4, l15 = lane & 15;
  const int swz = l15 & 7;
  const int bh = blockIdx.y;
  const int qb = blockIdx.x;
  const size_t hoff = (size_t)bh * (S * HD);   // same flat offset for [S,HD] and [HD,S]

  short8 aq0, aq1;
  {
    const u16* qp = Qg + hoff + (size_t)(qb*64 + wid*16 + l15) * HD;
    aq0 = *(const short8*)(qp + 8*l4);
    aq1 = *(const short8*)(qp + 32 + 8*l4);
  }

  float mr = -1e30f, lr = 0.f;                 // per-row max (replicated), per-LANE partial sum
  f32x4 oacc[4];
  #pragma unroll
  for (int hb=0;hb<4;hb++) oacc[hb] = (f32x4){0.f,0.f,0.f,0.f};

  const char* Kb = (const char*)(Kg  + hoff);
  const char* Vb = (const char*)(Vtg + hoff);
  char* KsB = (char*)Ks;
  char* VsB = (char*)Vs;
  char* PsB = (char*)Ps + wid*2048;

  int ldsu[2], srcK[2], srcV[2];
  #pragma unroll
  for (int p=0;p<2;p++){
    ldsu[p] = wid*2048 + p*1024;                 // wave-uniform base within one 8KB tile
    int b   = ldsu[p] + lane*16;                 // dest byte in tile
    int row = b >> 7, cc = (b >> 4) & 7;         // 128B rows, 16B chunks
    int ccs = cc ^ (row & 7);                    // pre-swizzled source chunk
    srcK[p] = row*128  + (ccs << 4);             // K tile contiguous (row stride 128B)
    srcV[p] = row*4096 + (ccs << 4);             // Vt row stride S*2 = 4096B
  }

  // prologue: stage tile 0 into buf 0
  {
    #pragma unroll
    for (int p=0;p<2;p++){
      gload_lds16(Kb + srcK[p], KsB + ldsu[p]);
      gload_lds16(Vb + srcV[p], VsB + ldsu[p]);
    }
  }
  __syncthreads();

  #pragma unroll 2
  for (int kt = 0; kt < S/64; ++kt){
    const int cur = kt & 1;
    // issue next tile's stage (overlaps with this tile's compute)
    if (kt + 1 < S/64){
      const int nxt = cur ^ 1;
      const char* Ksrc = Kb + (size_t)(kt+1)*8192;
      const char* Vsrc = Vb + (size_t)(kt+1)*128;
      #pragma unroll
      for (int p=0;p<2;p++){
        gload_lds16(Ksrc + srcK[p], KsB + nxt*8192 + ldsu[p]);
        gload_lds16(Vsrc + srcV[p], VsB + nxt*8192 + ldsu[p]);
      }
    }

    const char* KsC = KsB + cur*8192;
    const char* VsC = VsB + cur*8192;

    // S^T tile: mfma(A=K_frag, B=Q_frag) -> lane holds q = l15, kv = nb*16 + l4*4 + r
    f32x4 sacc[4];
    __builtin_amdgcn_s_setprio(1);
    #pragma unroll
    for (int nb=0;nb<4;nb++){
      const int krow = nb*16 + l15;
      short8 k0 = *(const short8*)(KsC + krow*128 + ((l4 ^ swz) << 4));
      short8 k1 = *(const short8*)(KsC + krow*128 + (((4 + l4) ^ swz) << 4));
      f32x4 zz = (f32x4){0.f,0.f,0.f,0.f};
      zz = __builtin_amdgcn_mfma_f32_16x16x32_bf16(k0, aq0, zz, 0,0,0);
      zz = __builtin_amdgcn_mfma_f32_16x16x32_bf16(k1, aq1, zz, 0,0,0);
      sacc[nb] = zz;
    }
    __builtin_amdgcn_s_setprio(0);

    // per-lane partial max over this lane's 16 kv (max3-friendly nesting)
    float t0 = fmaxf(fmaxf(sacc[0][0], sacc[0][1]), fmaxf(sacc[0][2], sacc[0][3]));
    float t1 = fmaxf(fmaxf(sacc[1][0], sacc[1][1]), fmaxf(sacc[1][2], sacc[1][3]));
    float t2 = fmaxf(fmaxf(sacc[2][0], sacc[2][1]), fmaxf(sacc[2][2], sacc[2][3]));
    float t3 = fmaxf(fmaxf(sacc[3][0], sacc[3][1]), fmaxf(sacc[3][2], sacc[3][3]));
    float t = fmaxf(fmaxf(t0, t1), fmaxf(t2, t3));

    // defer-max: rescale only when some row grew past THR=8 (exp2 domain -> P <= 256).
    // Ballot on per-lane partials; full per-row reduce only on trigger.
    if (!__all(t <= mr + 8.f)){
      float tw = fmaxf(t, __shfl_xor(t, 16, 64));
      tw = fmaxf(tw, __shfl_xor(tw, 32, 64));          // per-row tile max
      const float mnew = fmaxf(mr, tw);
      const float alpha = fast_exp2(mr - mnew);        // per-row
      mr = mnew;
      lr *= alpha;
      float af[4];
      #pragma unroll
      for (int r=0;r<4;r++) af[r] = __shfl(alpha, 4*l4 + r, 64);
      #pragma unroll
      for (int hb=0;hb<4;hb++)
        #pragma unroll
        for (int r=0;r<4;r++) oacc[hb][r] *= af[r];
    }

    float rs = 0.f;
    #pragma unroll
    for (int nb=0;nb<4;nb++)
      #pragma unroll
      for (int r=0;r<4;r++){
        float p = fast_exp2(sacc[nb][r] - mr);
        sacc[nb][r] = p;
        rs += p;
      }
    lr += rs;                                          // per-lane partial; reduced at end

    // P row (q=l15) -> per-wave LDS via packed cvt, swizzled to match A-frag read
    #pragma unroll
    for (int nb=0;nb<4;nb++){
      u32 lo = cvt_pk_bf16(sacc[nb][0], sacc[nb][1]);
      u32 hi = cvt_pk_bf16(sacc[nb][2], sacc[nb][3]);
      const int chunk = nb*2 + (l4 >> 1);
      const int sub   = (l4 & 1) * 8;
      *(uint2*)(PsB + l15*128 + ((chunk ^ swz) << 4) + sub) = make_uint2(lo, hi);
    }

    // O += P V
    __builtin_amdgcn_s_setprio(1);
    #pragma unroll
    for (int ks=0;ks<2;ks++){
      short8 ap = *(const short8*)(PsB + l15*128 + (((ks*4 + l4) ^ swz) << 4));
      #pragma unroll
      for (int hb=0;hb<4;hb++){
        const int vrow = hb*16 + l15;
        short8 bv = *(const short8*)(VsC + vrow*128 + (((ks*4 + l4) ^ swz) << 4));
        oacc[hb] = __builtin_amdgcn_mfma_f32_16x16x32_bf16(ap, bv, oacc[hb], 0,0,0);
      }
    }
    __builtin_amdgcn_s_setprio(0);
    __syncthreads();   // drains stage(kt+1) vmem + orders buffer reuse
  }

  // epilogue: finish the deferred row-sum reduce, normalize, store
  lr += __shfl_xor(lr, 16, 64);
  lr += __shfl_xor(lr, 32, 64);
  float inv[4];
  #pragma unroll
  for (int r=0;r<4;r++){
    float lq = __shfl(lr, 4*l4 + r, 64);
    inv[r] = 1.0f / lq;
  }
  const int b = bh >> 4, h = bh & 15;
  #pragma unroll
  for (int hb=0;hb<4;hb++){
    #pragma unroll
    for (int r=0;r<4;r++){
      const int si = qb*64 + wid*16 + 4*l4 + r;
      const float v = oacc[hb][r] * inv[r];
      Og[(((size_t)(b*S + si))*H + h)*HD + hb*16 + l15] = f2bf(v);
    }
  }
}

extern "C" void kernel_launch(void* const* d_in, const int* in_sizes, int n_in,
                              void* d_out, int out_size, void* d_ws, size_t ws_size,
                              hipStream_t stream) {
  const float* x  = (const float*)d_in[0];
  const float* Wq = (const float*)d_in[1];
  const float* bq = (const float*)d_in[2];
  const float* Wk = (const float*)d_in[3];
  const float* bk = (const float*)d_in[4];
  const float* Wv = (const float*)d_in[5];
  const float* bv = (const float*)d_in[6];
  const float* Wo = (const float*)d_in[7];
  const float* bo = (const float*)d_in[8];

  char* ws = (char*)d_ws;
  // layout (bytes): xb 0..8M | Wb 8M..16M (Wq,Wk,Wv,Wo) | Q 16M | K 24M | Vt 32M | AO 40M..48M
  u16* xb  = (u16*)(ws);
  u16* Wb  = (u16*)(ws + (size_t)8*1024*1024);
  u16* QKV = (u16*)(ws + (size_t)16*1024*1024);
  u16* AO  = (u16*)(ws + (size_t)40*1024*1024);
  float* out = (float*)d_out;

  cast_f32_bf16<<<4096, 256, 0, stream>>>(x, xb, 4194304);
  cast_w4<<<4096, 256, 0, stream>>>(Wq, Wk, Wv, Wo, Wb);

  dim3 g1(8, 32, 3);
  gemm_bt<0><<<g1, 256, 0, stream>>>(xb, Wb, bq, bk, bv, QKV, nullptr);

  dim3 g2(32, 32, 1);
  attn_fwd<<<g2, 256, 0, stream>>>(QKV, QKV + 4194304, QKV + 2*4194304, AO);

  dim3 g3(8, 32, 1);
  gemm_bt<1><<<g3, 256, 0, stream>>>(AO, Wb + 3145728, bo, bo, bo, nullptr, out);
}

// Round 6
// 138.875 us; speedup vs baseline: 1.5872x; 1.0442x over previous
//
#include <hip/hip_runtime.h>
#include <hip/hip_bf16.h>
#include <stdint.h>

typedef __attribute__((ext_vector_type(8))) short short8;
typedef __attribute__((ext_vector_type(4))) float f32x4;
typedef unsigned short u16;
typedef unsigned int u32;

static constexpr int S = 2048;
static constexpr int H = 16;
static constexpr int HD = 64;

__device__ __forceinline__ float fast_exp2(float x){
  return __builtin_amdgcn_exp2f(x);
}

__device__ __forceinline__ u16 f2bf(float f){
  union { float f; u32 u; } x; x.f = f;
  u32 r = x.u + 0x7fffu + ((x.u >> 16) & 1u);
  return (u16)(r >> 16);
}

// packed RNE f32x2 -> bf16x2 (no builtin on gfx950; single VALU op)
__device__ __forceinline__ u32 cvt_pk_bf16(float lo, float hi){
  u32 r;
  asm("v_cvt_pk_bf16_f32 %0, %1, %2" : "=v"(r) : "v"(lo), "v"(hi));
  return r;
}

__global__ __launch_bounds__(256) void cast_f32_bf16(const float* __restrict__ src,
                                                     u16* __restrict__ dst, int n){
  int i = (blockIdx.x * 256 + threadIdx.x) * 4;
  if (i >= n) return;
  float4 v = *(const float4*)(src + i);
  ushort4 o;
  o.x = f2bf(v.x); o.y = f2bf(v.y); o.z = f2bf(v.z); o.w = f2bf(v.w);
  *(ushort4*)(dst + i) = o;
}

// 4 weight matrices (1M elems each) -> contiguous bf16 dst
__global__ __launch_bounds__(256) void cast_w4(const float* __restrict__ a,
                                               const float* __restrict__ b,
                                               const float* __restrict__ c,
                                               const float* __restrict__ d,
                                               u16* __restrict__ dst){
  int i = (blockIdx.x * 256 + threadIdx.x) * 4;
  const float* s = (i < 2097152) ? ((i < 1048576) ? a : b)
                                 : ((i < 3145728) ? c : d);
  float4 v = *(const float4*)(s + (i & 1048575));
  ushort4 o;
  o.x = f2bf(v.x); o.y = f2bf(v.y); o.z = f2bf(v.z); o.w = f2bf(v.w);
  *(ushort4*)(dst + i) = o;
}

__device__ __forceinline__ void gload_lds16(const void* g, void* lds_uniform){
  __builtin_amdgcn_global_load_lds(
      (const __attribute__((address_space(1))) u32*)g,
      (__attribute__((address_space(3))) u32*)lds_uniform,
      16, 0, 0);
}

// C = A * W^T + bias.  A: [M x 1024] bf16 row-major. W: [1024 x 1024] bf16 (out,in).
// EPI==0: QKV. z=0 (Q, pre-scaled by 0.125*log2e) , z=1 (K) -> bf16 [B,H,S,HD];
//         z=2 (V) -> bf16 [B,H,HD,S] (transposed).  grid (8,32,3), XCD-swizzled.
// EPI==1: write fp32 [M,1024].  grid (8,32,1), XCD-swizzled.
template<int EPI>
__global__ __launch_bounds__(256) void gemm_bt(const u16* __restrict__ A,
                                               const u16* __restrict__ Wall,
                                               const float* __restrict__ b0p,
                                               const float* __restrict__ b1p,
                                               const float* __restrict__ b2p,
                                               u16* __restrict__ obf,
                                               float* __restrict__ ofp){
  __shared__ __align__(16) u16 As[128*32];
  __shared__ __align__(16) u16 Bs[128*32];

  const int tid  = threadIdx.x;
  const int lane = tid & 63;
  const int wid  = tid >> 6;
  const int wm = wid >> 1, wn = wid & 1;
  const int l4 = lane >> 4, l15 = lane & 15;

  // XCD-aware bijective swizzle (grid sizes divisible by 8):
  // hw linear id L -> work id W so each XCD gets a contiguous chunk.
  int m0, n0, z;
  if (EPI == 0){
    const int L = blockIdx.x + 8*blockIdx.y + 256*blockIdx.z;   // [0,768)
    const int W = (L & 7)*96 + (L >> 3);
    z = W >> 8;
    const int rem = W & 255;
    n0 = (rem & 7) * 128;
    m0 = (rem >> 3) * 128;
  } else {
    const int L = blockIdx.x + 8*blockIdx.y;                    // [0,256)
    const int W = (L & 7)*32 + (L >> 3);
    z = 0;
    n0 = (W & 7) * 128;
    m0 = (W >> 3) * 128;
  }

  const u16* Bw = Wall + (size_t)z * (1024*1024);
  const float* bias = (z == 0) ? b0p : ((z == 1) ? b1p : b2p);

  f32x4 acc[4][4];
  #pragma unroll
  for (int m=0;m<4;m++)
    #pragma unroll
    for (int n=0;n<4;n++) acc[m][n] = (f32x4){0.f,0.f,0.f,0.f};

  const char* Ab = (const char*)A  + (size_t)m0 * 2048;   // row stride = 1024*2B
  const char* Bb = (const char*)Bw + (size_t)n0 * 2048;
  char* AsB = (char*)As;
  char* BsB = (char*)Bs;

  int ldsu[2], row_[2], col_[2];
  #pragma unroll
  for (int p=0;p<2;p++){
    ldsu[p] = wid*1024 + p*4096;          // wave-uniform LDS byte base
    int b = ldsu[p] + lane*16;            // this lane's 16B chunk
    row_[p] = b >> 6;                     // tile row (64B per row: 32 bf16)
    col_[p] = b & 63;                     // byte within row
  }

  for (int kt = 0; kt < 32; ++kt){
    const int kb = kt * 64;               // K byte offset
    #pragma unroll
    for (int p=0;p<2;p++){
      gload_lds16(Ab + (size_t)row_[p]*2048 + kb + col_[p], AsB + ldsu[p]);
      gload_lds16(Bb + (size_t)row_[p]*2048 + kb + col_[p], BsB + ldsu[p]);
    }
    __syncthreads();

    short8 af[4], bfr[4];
    const int kcol = 8 * l4;
    #pragma unroll
    for (int m=0;m<4;m++)
      af[m] = *(const short8*)&As[(wm*64 + m*16 + l15)*32 + kcol];
    #pragma unroll
    for (int n=0;n<4;n++)
      bfr[n] = *(const short8*)&Bs[(wn*64 + n*16 + l15)*32 + kcol];

    #pragma unroll
    for (int m=0;m<4;m++)
      #pragma unroll
      for (int n=0;n<4;n++)
        acc[m][n] = __builtin_amdgcn_mfma_f32_16x16x32_bf16(af[m], bfr[n], acc[m][n], 0,0,0);

    __syncthreads();
  }

  #pragma unroll
  for (int m=0;m<4;m++){
    const int rgb = m0 + wm*64 + m*16 + 4*l4;
    #pragma unroll
    for (int n=0;n<4;n++){
      const int cg = n0 + wn*64 + n*16 + l15;
      const float bb = bias[cg];
      if (EPI == 0){
        const int bi = rgb >> 11, si = rgb & 2047;   // 4 rows share bi (rgb % 4 == 0)
        const int hi = cg >> 6,  hd = cg & 63;
        if (z == 2){
          // V transposed: [B,H,HD,S], pack 4 consecutive tokens -> 8B store
          u16* outz = obf + (size_t)2 * 4194304u;
          ushort4 o;
          o.x = f2bf(acc[m][n][0] + bb);
          o.y = f2bf(acc[m][n][1] + bb);
          o.z = f2bf(acc[m][n][2] + bb);
          o.w = f2bf(acc[m][n][3] + bb);
          *(ushort4*)&outz[(((size_t)(bi*16 + hi))*64 + hd)*2048 + si] = o;
        } else {
          u16* outz = obf + (size_t)z * 4194304u;
          // Q pre-scaled so attention scores are already in exp2 domain:
          // score*log2e/sqrt(64) folded here.
          const float sc = (z == 0) ? 0.18033688011112042f : 1.0f;
          #pragma unroll
          for (int r=0;r<4;r++)
            outz[(((size_t)(bi*16 + hi))*2048 + (si + r))*64 + hd] =
                f2bf((acc[m][n][r] + bb) * sc);
        }
      } else {
        #pragma unroll
        for (int r=0;r<4;r++)
          ofp[(size_t)(rgb + r)*1024 + cg] = acc[m][n][r] + bb;
      }
    }
  }
}

// Flash attention, swapped-QK^T, 2 q-groups (32 q-rows) per wave, K/V dbuf.
// Q,K: bf16 [B,H,S,HD] (Q pre-scaled). Vt: bf16 [B,H,HD,S]. Out: bf16 [B,S,H,HD].
// grid = (S/128, B*H) = (16,32), 256 threads (4 waves x 32 q-rows = 128 rows/block).
__global__ __launch_bounds__(256) void attn_fwd(const u16* __restrict__ Qg,
                                                const u16* __restrict__ Kg,
                                                const u16* __restrict__ Vtg,
                                                u16* __restrict__ Og){
  __shared__ __align__(16) u16 Ks[2*64*64];      // 2 bufs, XOR-swizzled rows (kv x hd)
  __shared__ __align__(16) u16 Vs[2*64*64];      // 2 bufs, XOR-swizzled rows (hd x kv)
  __shared__ __align__(16) u16 Ps[4*2*16*64];    // per-wave x 2 groups, swizzled

  const int tid  = threadIdx.x;
  const int lane = tid & 63;
  const int wid  = tid >> 6;
  const int l4 = lane >> 4, l15 = lane & 15;
  const int swz = l15 & 7;

  // XCD swizzle: cluster all 16 q-tiles of each (b,h) onto one XCD (KV L2 reuse)
  const int L = blockIdx.x + 16*blockIdx.y;      // [0,512)
  const int W = (L & 7)*64 + (L >> 3);
  const int qb = W & 15;
  const int bh = W >> 4;
  const size_t hoff = (size_t)bh * (S * HD);     // same flat offset for [S,HD] and [HD,S]

  // two 16-row Q fragment groups per wave
  short8 aq[2][2];
  #pragma unroll
  for (int g=0; g<2; ++g){
    const u16* qp = Qg + hoff + (size_t)(qb*128 + wid*32 + g*16 + l15) * HD;
    aq[g][0] = *(const short8*)(qp + 8*l4);
    aq[g][1] = *(const short8*)(qp + 32 + 8*l4);
  }

  float mr[2] = {-1e30f, -1e30f};
  float lr[2] = {0.f, 0.f};                      // per-LANE partial sums
  f32x4 oacc[2][4];
  #pragma unroll
  for (int g=0; g<2; ++g)
    #pragma unroll
    for (int hb=0;hb<4;hb++) oacc[g][hb] = (f32x4){0.f,0.f,0.f,0.f};

  const char* Kb = (const char*)(Kg  + hoff);
  const char* Vb = (const char*)(Vtg + hoff);
  char* KsB = (char*)Ks;
  char* VsB = (char*)Vs;
  char* PsB = (char*)Ps + wid*4096;              // 2 groups x 2KB

  int ldsu[2], srcK[2], srcV[2];
  #pragma unroll
  for (int p=0;p<2;p++){
    ldsu[p] = wid*2048 + p*1024;                 // wave-uniform base within one 8KB tile
    int b   = ldsu[p] + lane*16;                 // dest byte in tile
    int row = b >> 7, cc = (b >> 4) & 7;         // 128B rows, 16B chunks
    int ccs = cc ^ (row & 7);                    // pre-swizzled source chunk
    srcK[p] = row*128  + (ccs << 4);             // K tile contiguous (row stride 128B)
    srcV[p] = row*4096 + (ccs << 4);             // Vt row stride S*2 = 4096B
  }

  // prologue: stage tile 0 into buf 0
  #pragma unroll
  for (int p=0;p<2;p++){
    gload_lds16(Kb + srcK[p], KsB + ldsu[p]);
    gload_lds16(Vb + srcV[p], VsB + ldsu[p]);
  }
  __syncthreads();

  #pragma unroll 2
  for (int kt = 0; kt < S/64; ++kt){
    const int cur = kt & 1;
    // issue next tile's stage (overlaps with this tile's compute)
    if (kt + 1 < S/64){
      const int nxt = cur ^ 1;
      const char* Ksrc = Kb + (size_t)(kt+1)*8192;
      const char* Vsrc = Vb + (size_t)(kt+1)*128;
      #pragma unroll
      for (int p=0;p<2;p++){
        gload_lds16(Ksrc + srcK[p], KsB + nxt*8192 + ldsu[p]);
        gload_lds16(Vsrc + srcV[p], VsB + nxt*8192 + ldsu[p]);
      }
    }

    const char* KsC = KsB + cur*8192;
    const char* VsC = VsB + cur*8192;

    // S^T tile: mfma(A=K_frag, B=Q_frag); K-frags read once, used by both groups
    f32x4 sacc[2][4];
    __builtin_amdgcn_s_setprio(1);
    #pragma unroll
    for (int nb=0;nb<4;nb++){
      const int krow = nb*16 + l15;
      short8 k0 = *(const short8*)(KsC + krow*128 + ((l4 ^ swz) << 4));
      short8 k1 = *(const short8*)(KsC + krow*128 + (((4 + l4) ^ swz) << 4));
      #pragma unroll
      for (int g=0; g<2; ++g){
        f32x4 zz = (f32x4){0.f,0.f,0.f,0.f};
        zz = __builtin_amdgcn_mfma_f32_16x16x32_bf16(k0, aq[g][0], zz, 0,0,0);
        zz = __builtin_amdgcn_mfma_f32_16x16x32_bf16(k1, aq[g][1], zz, 0,0,0);
        sacc[g][nb] = zz;
      }
    }
    __builtin_amdgcn_s_setprio(0);

    #pragma unroll
    for (int g=0; g<2; ++g){
      // per-lane partial max over this lane's 16 kv
      float t0 = fmaxf(fmaxf(sacc[g][0][0], sacc[g][0][1]), fmaxf(sacc[g][0][2], sacc[g][0][3]));
      float t1 = fmaxf(fmaxf(sacc[g][1][0], sacc[g][1][1]), fmaxf(sacc[g][1][2], sacc[g][1][3]));
      float t2 = fmaxf(fmaxf(sacc[g][2][0], sacc[g][2][1]), fmaxf(sacc[g][2][2], sacc[g][2][3]));
      float t3 = fmaxf(fmaxf(sacc[g][3][0], sacc[g][3][1]), fmaxf(sacc[g][3][2], sacc[g][3][3]));
      float t = fmaxf(fmaxf(t0, t1), fmaxf(t2, t3));

      // defer-max: rescale only when some row grew past THR=8 (exp2 domain -> P <= 256)
      if (!__all(t <= mr[g] + 8.f)){
        float tw = fmaxf(t, __shfl_xor(t, 16, 64));
        tw = fmaxf(tw, __shfl_xor(tw, 32, 64));        // per-row tile max
        const float mnew = fmaxf(mr[g], tw);
        const float alpha = fast_exp2(mr[g] - mnew);   // per-row
        mr[g] = mnew;
        lr[g] *= alpha;
        float af[4];
        #pragma unroll
        for (int r=0;r<4;r++) af[r] = __shfl(alpha, 4*l4 + r, 64);
        #pragma unroll
        for (int hb=0;hb<4;hb++)
          #pragma unroll
          for (int r=0;r<4;r++) oacc[g][hb][r] *= af[r];
      }

      float rs = 0.f;
      #pragma unroll
      for (int nb=0;nb<4;nb++)
        #pragma unroll
        for (int r=0;r<4;r++){
          float p = fast_exp2(sacc[g][nb][r] - mr[g]);
          sacc[g][nb][r] = p;
          rs += p;
        }
      lr[g] += rs;                                     // per-lane partial; reduced at end

      // P row (q=l15) -> per-wave LDS via packed cvt, swizzled to match A-frag read
      #pragma unroll
      for (int nb=0;nb<4;nb++){
        u32 lo = cvt_pk_bf16(sacc[g][nb][0], sacc[g][nb][1]);
        u32 hi = cvt_pk_bf16(sacc[g][nb][2], sacc[g][nb][3]);
        const int chunk = nb*2 + (l4 >> 1);
        const int sub   = (l4 & 1) * 8;
        *(uint2*)(PsB + g*2048 + l15*128 + ((chunk ^ swz) << 4) + sub) = make_uint2(lo, hi);
      }
    }

    // O += P V  (V-frags read once, used by both groups)
    __builtin_amdgcn_s_setprio(1);
    #pragma unroll
    for (int ks=0;ks<2;ks++){
      short8 ap0 = *(const short8*)(PsB +        l15*128 + (((ks*4 + l4) ^ swz) << 4));
      short8 ap1 = *(const short8*)(PsB + 2048 + l15*128 + (((ks*4 + l4) ^ swz) << 4));
      #pragma unroll
      for (int hb=0;hb<4;hb++){
        const int vrow = hb*16 + l15;
        short8 bv = *(const short8*)(VsC + vrow*128 + (((ks*4 + l4) ^ swz) << 4));
        oacc[0][hb] = __builtin_amdgcn_mfma_f32_16x16x32_bf16(ap0, bv, oacc[0][hb], 0,0,0);
        oacc[1][hb] = __builtin_amdgcn_mfma_f32_16x16x32_bf16(ap1, bv, oacc[1][hb], 0,0,0);
      }
    }
    __builtin_amdgcn_s_setprio(0);
    __syncthreads();   // drains stage(kt+1) vmem + orders buffer reuse
  }

  // epilogue: finish the deferred row-sum reduce, normalize, store
  const int b = bh >> 4, h = bh & 15;
  #pragma unroll
  for (int g=0; g<2; ++g){
    float lg = lr[g];
    lg += __shfl_xor(lg, 16, 64);
    lg += __shfl_xor(lg, 32, 64);
    float inv[4];
    #pragma unroll
    for (int r=0;r<4;r++){
      float lq = __shfl(lg, 4*l4 + r, 64);
      inv[r] = 1.0f / lq;
    }
    #pragma unroll
    for (int hb=0;hb<4;hb++){
      #pragma unroll
      for (int r=0;r<4;r++){
        const int si = qb*128 + wid*32 + g*16 + 4*l4 + r;
        const float v = oacc[g][hb][r] * inv[r];
        Og[(((size_t)(b*S + si))*H + h)*HD + hb*16 + l15] = f2bf(v);
      }
    }
  }
}

extern "C" void kernel_launch(void* const* d_in, const int* in_sizes, int n_in,
                              void* d_out, int out_size, void* d_ws, size_t ws_size,
                              hipStream_t stream) {
  const float* x  = (const float*)d_in[0];
  const float* Wq = (const float*)d_in[1];
  const float* bq = (const float*)d_in[2];
  const float* Wk = (const float*)d_in[3];
  const float* bk = (const float*)d_in[4];
  const float* Wv = (const float*)d_in[5];
  const float* bv = (const float*)d_in[6];
  const float* Wo = (const float*)d_in[7];
  const float* bo = (const float*)d_in[8];

  char* ws = (char*)d_ws;
  // layout (bytes): xb 0..8M | Wb 8M..16M (Wq,Wk,Wv,Wo) | Q 16M | K 24M | Vt 32M | AO 40M..48M
  u16* xb  = (u16*)(ws);
  u16* Wb  = (u16*)(ws + (size_t)8*1024*1024);
  u16* QKV = (u16*)(ws + (size_t)16*1024*1024);
  u16* AO  = (u16*)(ws + (size_t)40*1024*1024);
  float* out = (float*)d_out;

  cast_f32_bf16<<<4096, 256, 0, stream>>>(x, xb, 4194304);
  cast_w4<<<4096, 256, 0, stream>>>(Wq, Wk, Wv, Wo, Wb);

  dim3 g1(8, 32, 3);
  gemm_bt<0><<<g1, 256, 0, stream>>>(xb, Wb, bq, bk, bv, QKV, nullptr);

  dim3 g2(16, 32, 1);
  attn_fwd<<<g2, 256, 0, stream>>>(QKV, QKV + 4194304, QKV + 2*4194304, AO);

  dim3 g3(8, 32, 1);
  gemm_bt<1><<<g3, 256, 0, stream>>>(AO, Wb + 3145728, bo, bo, bo, nullptr, out);
}